// Round 7
// baseline (106.309 us; speedup 1.0000x reference)
//
#include <hip/hip_runtime.h>
#include <hip/hip_bf16.h>

#define BDIM 4096
#define DDIM 512
#define BTI 128                  // rows per block
#define BTJ 64                   // cols per block
#define BK 32                    // K per tile-step
#define NKT (DDIM / BK)          // 16
#define NBLK 1056                // triangle blocks: sum_{I=0}^{31}(64-2I)

typedef __bf16 bf16x8 __attribute__((ext_vector_type(8)));
typedef float f32x4 __attribute__((ext_vector_type(4)));
typedef unsigned short ushort_t;

#define WAITV3() asm volatile("s_waitcnt vmcnt(3)" ::: "memory")
#define WAITV0() asm volatile("s_waitcnt vmcnt(0)" ::: "memory")
#define WAITL0() asm volatile("s_waitcnt lgkmcnt(0)" ::: "memory")

__device__ inline ushort_t f2bf(float f) {
  __hip_bfloat16 h = __float2bfloat16(f);
  return *reinterpret_cast<ushort_t*>(&h);
}

// order-preserving float <-> uint mapping (monotonic) for atomic min/max
__device__ inline unsigned int enc_f32(float x) {
  unsigned int u = __float_as_uint(x);
  return (u & 0x80000000u) ? ~u : (u | 0x80000000u);
}
__device__ inline float dec_f32(unsigned int e) {
  unsigned int u = (e & 0x80000000u) ? (e ^ 0x80000000u) : ~e;
  return __uint_as_float(u);
}

// ---------------- kernel 1: L2-normalize rows, emit bf16; init state -----
__global__ __launch_bounds__(256) void norm_kernel(const float* __restrict__ x,
                                                   ushort_t* __restrict__ e,
                                                   unsigned int* __restrict__ minpos_e,
                                                   unsigned int* __restrict__ maxneg_e,
                                                   unsigned int* __restrict__ done_ctr) {
  if (blockIdx.x == 0) {  // init (stream order: completes before gemm launch)
    const unsigned int init_min = enc_f32(1e30f);
    const unsigned int init_max = enc_f32(-1e30f);
    for (int i = threadIdx.x; i < BDIM; i += 256) {
      minpos_e[i] = init_min;
      maxneg_e[i] = init_max;
    }
    if (threadIdx.x == 0) done_ctr[0] = 0u;
  }
  const int row  = blockIdx.x * 4 + (threadIdx.x >> 6);
  const int lane = threadIdx.x & 63;
  const float4* xr = reinterpret_cast<const float4*>(x + (size_t)row * DDIM);
  float4 v0 = xr[lane];
  float4 v1 = xr[lane + 64];
  float ss = v0.x*v0.x + v0.y*v0.y + v0.z*v0.z + v0.w*v0.w
           + v1.x*v1.x + v1.y*v1.y + v1.z*v1.z + v1.w*v1.w;
#pragma unroll
  for (int off = 32; off >= 1; off >>= 1) ss += __shfl_xor(ss, off);
  const float inv = 1.0f / fmaxf(sqrtf(ss), 1e-12f);

  ushort4 p0, p1;
  p0.x = f2bf(v0.x * inv); p0.y = f2bf(v0.y * inv);
  p0.z = f2bf(v0.z * inv); p0.w = f2bf(v0.w * inv);
  p1.x = f2bf(v1.x * inv); p1.y = f2bf(v1.y * inv);
  p1.z = f2bf(v1.z * inv); p1.w = f2bf(v1.w * inv);
  ushort4* er = reinterpret_cast<ushort4*>(e + (size_t)row * DDIM);
  er[lane]      = p0;
  er[lane + 64] = p1;
}

// --- kernel 2: triangle GEMM, 3-buffer counted-vmcnt pipeline, fused end ---
// Per buffer: A [128 rows][32 k] bf16 (8 KB) + B [64 rows][32 k] (4 KB).
// Row stride 64 B: stage-writes and frag-reads are byte-contiguous per wave
// -> zero bank conflicts, no swizzle needed. 3 loads/thread per STAGE.
#define STAGE(bi, kt)                                                          \
  do {                                                                         \
    _Pragma("unroll")                                                          \
    for (int q = 0; q < 2; ++q) {  /* A: rows 0..127 */                        \
      const int off = q * 4096 + tid * 16;                                     \
      const int row = off >> 6;                                                \
      const char* src = (const char*)e + (size_t)(Ibase + row) * (DDIM * 2) +  \
                        (kt) * 64 + (off & 63);                                \
      __builtin_amdgcn_global_load_lds(                                        \
          (const __attribute__((address_space(1))) void*)src,                  \
          (__attribute__((address_space(3))) void*)(&Blds[bi][off]),           \
          16, 0, 0);                                                           \
    }                                                                          \
    {  /* B: rows 0..63 */                                                     \
      const int boff = tid * 16;                                               \
      const int brow = boff >> 6;                                              \
      const char* bsrc = (const char*)e + (size_t)(Jbase + brow) * (DDIM * 2) +\
                         (kt) * 64 + (boff & 63);                              \
      __builtin_amdgcn_global_load_lds(                                        \
          (const __attribute__((address_space(1))) void*)bsrc,                 \
          (__attribute__((address_space(3))) void*)(&Blds[bi][8192 + boff]),   \
          16, 0, 0);                                                           \
    }                                                                          \
  } while (0)

__global__ __launch_bounds__(256, 4) void gemm_reduce_kernel(
    const ushort_t* __restrict__ e, const int* __restrict__ labels,
    unsigned int* __restrict__ minpos_e, unsigned int* __restrict__ maxneg_e,
    unsigned int* __restrict__ done_ctr, float* __restrict__ out) {
  __shared__ __align__(16) char Blds[3][12288];
  __shared__ int lastflag;
  __shared__ float wsum[4];
  __shared__ int   wcnt[4];

  const int tid  = threadIdx.x;
  const int wave = tid >> 6;
  const int lane = tid & 63;
  const int l15  = lane & 15;
  const int g    = lane >> 4;     // 0..3
  const int wr   = wave >> 1;     // 0..1: 64-row half
  const int wc   = wave & 1;      // 0..1: 32-col half

  // bijective XCD swizzle over 1056 = 8*132 blocks, then triangle decode:
  // t enumerates pairs (I, h) with h >= 2I; offset(I) = I*(65-I)
  const int bid = blockIdx.x;
  const int t   = (bid & 7) * (NBLK / 8) + (bid >> 3);
  int I = (int)((65.0f - sqrtf(4225.0f - 4.0f * (float)t)) * 0.5f);
  if (I < 0) I = 0;
  if (I > 31) I = 31;
  while (I < 31 && (I + 1) * (65 - (I + 1)) <= t) ++I;
  while (I > 0 && I * (65 - I) > t) --I;
  const int h = 2 * I + (t - I * (65 - I));
  const int Ibase = I * BTI;
  const int Jbase = h * BTJ;

  f32x4 acc[4][2];
#pragma unroll
  for (int m = 0; m < 4; ++m)
#pragma unroll
    for (int n = 0; n < 2; ++n) acc[m][n] = (f32x4){0.f, 0.f, 0.f, 0.f};

  STAGE(0, 0);
  STAGE(1, 1);

#pragma unroll
  for (int kt = 0; kt < NKT; ++kt) {
    if (kt < NKT - 1) { WAITV3(); } else { WAITV0(); }  // counted: stage(kt) done, stage(kt+1) in flight
    WAITL0();                                           // prev ds_reads complete before barrier
    __builtin_amdgcn_sched_barrier(0);
    __builtin_amdgcn_s_barrier();
    __builtin_amdgcn_sched_barrier(0);
    if (kt + 2 < NKT) STAGE((kt + 2) % 3, kt + 2);      // into buffer freed at last barrier

    const char* Ab = Blds[kt % 3];
    const char* Bb = Ab + 8192;
    bf16x8 a[4], b[2];
#pragma unroll
    for (int m = 0; m < 4; ++m)
      a[m] = *reinterpret_cast<const bf16x8*>(Ab + (wr * 64 + m * 16 + l15) * 64 + g * 16);
#pragma unroll
    for (int n = 0; n < 2; ++n)
      b[n] = *reinterpret_cast<const bf16x8*>(Bb + (wc * 32 + n * 16 + l15) * 64 + g * 16);

    __builtin_amdgcn_s_setprio(1);
#pragma unroll
    for (int m = 0; m < 4; ++m)
#pragma unroll
      for (int n = 0; n < 2; ++n)
        acc[m][n] = __builtin_amdgcn_mfma_f32_16x16x32_bf16(a[m], b[n],
                                                            acc[m][n], 0, 0, 0);
    __builtin_amdgcn_s_setprio(0);
  }

  // ---- fused epilogue: dual-direction masked min/max --------------------
  // C/D 16x16 layout: col = l15, row = g*4 + r.
  float cmp[2], cmx[2];
  int lj[2], gj[2];
#pragma unroll
  for (int n = 0; n < 2; ++n) {
    cmp[n] = 1e30f; cmx[n] = -1e30f;
    gj[n]  = Jbase + wc * 32 + n * 16 + l15;
    lj[n]  = labels[gj[n]];
  }
  float rmp[4][4], rmx[4][4];
#pragma unroll
  for (int m = 0; m < 4; ++m)
#pragma unroll
    for (int r = 0; r < 4; ++r) { rmp[m][r] = 1e30f; rmx[m][r] = -1e30f; }

#pragma unroll
  for (int m = 0; m < 4; ++m) {
#pragma unroll
    for (int r = 0; r < 4; ++r) {
      const int gi = Ibase + wr * 64 + m * 16 + g * 4 + r;
      const int li = labels[gi];
#pragma unroll
      for (int n = 0; n < 2; ++n) {
        const float v = acc[m][n][r];
        if (li == lj[n]) {
          if (gi != gj[n]) {
            rmp[m][r] = fminf(rmp[m][r], v);
            cmp[n]    = fminf(cmp[n], v);
          }
        } else {
          rmx[m][r] = fmaxf(rmx[m][r], v);
          cmx[n]    = fmaxf(cmx[n], v);
        }
      }
    }
  }

  // col reduce across g lanes (xor 16, 32)
#pragma unroll
  for (int off = 16; off <= 32; off <<= 1) {
#pragma unroll
    for (int n = 0; n < 2; ++n) {
      cmp[n] = fminf(cmp[n], __shfl_xor(cmp[n], off));
      cmx[n] = fmaxf(cmx[n], __shfl_xor(cmx[n], off));
    }
  }
  // row reduce across l15 lanes (xor 1,2,4,8)
#pragma unroll
  for (int off = 1; off < 16; off <<= 1) {
#pragma unroll
    for (int m = 0; m < 4; ++m)
#pragma unroll
      for (int r = 0; r < 4; ++r) {
        rmp[m][r] = fminf(rmp[m][r], __shfl_xor(rmp[m][r], off));
        rmx[m][r] = fmaxf(rmx[m][r], __shfl_xor(rmx[m][r], off));
      }
  }

  if (g == 0) {
#pragma unroll
    for (int n = 0; n < 2; ++n) {
      if (cmp[n] < 1e29f)  atomicMin(&minpos_e[gj[n]], enc_f32(cmp[n]));
      if (cmx[n] > -1e29f) atomicMax(&maxneg_e[gj[n]], enc_f32(cmx[n]));
    }
  }
  if (l15 == 0) {
#pragma unroll
    for (int m = 0; m < 4; ++m)
#pragma unroll
      for (int r = 0; r < 4; ++r) {
        const int gi = Ibase + wr * 64 + m * 16 + g * 4 + r;
        if (rmp[m][r] < 1e29f)  atomicMin(&minpos_e[gi], enc_f32(rmp[m][r]));
        if (rmx[m][r] > -1e29f) atomicMax(&maxneg_e[gi], enc_f32(rmx[m][r]));
      }
  }

  // ---- last-block-done finalize (replaces 3rd kernel launch) -------------
  __threadfence();   // release: our atomics visible before counter bump
  if (tid == 0) lastflag = (atomicAdd(done_ctr, 1u) == NBLK - 1);
  __syncthreads();
  if (lastflag) {
    __threadfence(); // acquire
    float sum = 0.f;
    int cnt = 0;
    for (int row = tid; row < BDIM; row += 256) {
      const unsigned int ump = __hip_atomic_load(&minpos_e[row], __ATOMIC_RELAXED,
                                                 __HIP_MEMORY_SCOPE_AGENT);
      const unsigned int umn = __hip_atomic_load(&maxneg_e[row], __ATOMIC_RELAXED,
                                                 __HIP_MEMORY_SCOPE_AGENT);
      const float mp = dec_f32(ump);
      const float mn = dec_f32(umn);
      if (mp < 1e29f && mn > -1e29f) {
        // hp - hn + margin = (1-mp) - (1-mn) + 0.2 = mn - mp + 0.2
        sum += fmaxf(0.f, mn - mp + 0.2f);
        cnt += 1;
      }
    }
#pragma unroll
    for (int off = 32; off >= 1; off >>= 1) {
      sum += __shfl_xor(sum, off);
      cnt += __shfl_xor(cnt, off);
    }
    if (lane == 0) { wsum[wave] = sum; wcnt[wave] = cnt; }
    __syncthreads();
    if (tid == 0) {
      float S = 0.f; int C = 0;
      for (int w = 0; w < 4; ++w) { S += wsum[w]; C += wcnt[w]; }
      out[0] = S / (float)(C > 0 ? C : 1);
    }
  }
}

extern "C" void kernel_launch(void* const* d_in, const int* in_sizes, int n_in,
                              void* d_out, int out_size, void* d_ws, size_t ws_size,
                              hipStream_t stream) {
  const float* x      = (const float*)d_in[0];
  const int*   labels = (const int*)d_in[1];
  float* out = (float*)d_out;

  char* ws = (char*)d_ws;
  ushort_t* e            = (ushort_t*)ws;                            // 4 MB bf16 E
  unsigned int* minpos_e = (unsigned int*)(ws + (size_t)BDIM * DDIM * 2);
  unsigned int* maxneg_e = minpos_e + BDIM;
  unsigned int* done_ctr = maxneg_e + BDIM;

  norm_kernel<<<BDIM / 4, 256, 0, stream>>>(x, e, minpos_e, maxneg_e, done_ctr);
  gemm_reduce_kernel<<<NBLK, 256, 0, stream>>>(e, labels, minpos_e, maxneg_e,
                                               done_ctr, out);
}

// Round 8
// 36.578 us; speedup vs baseline: 2.9063x; 2.9063x over previous
//
#include <hip/hip_runtime.h>
#include <hip/hip_bf16.h>

#define BDIM 4096
#define DDIM 512
#define BT 128                    // block tile (rows == cols)
#define BK 32                     // K per tile-step
#define NKT (DDIM / BK)           // 16 K tiles
#define NPAN (BDIM / BT)          // 32 panels
#define GRIDX (NPAN * NPAN)       // 1024 blocks

typedef __bf16 bf16x8 __attribute__((ext_vector_type(8)));
typedef float f32x4 __attribute__((ext_vector_type(4)));
typedef unsigned short ushort_t;

__device__ inline ushort_t f2bf(float f) {
  __hip_bfloat16 h = __float2bfloat16(f);
  return *reinterpret_cast<ushort_t*>(&h);
}

// order-preserving float <-> uint mapping (monotonic) for atomic min/max
__device__ inline unsigned int enc_f32(float x) {
  unsigned int u = __float_as_uint(x);
  return (u & 0x80000000u) ? ~u : (u | 0x80000000u);
}
__device__ inline float dec_f32(unsigned int e) {
  unsigned int u = (e & 0x80000000u) ? (e ^ 0x80000000u) : ~e;
  return __uint_as_float(u);
}

// ---------------- kernel 1: L2-normalize rows, emit bf16; init atomics -----
__global__ __launch_bounds__(256) void norm_kernel(const float* __restrict__ x,
                                                   ushort_t* __restrict__ e,
                                                   unsigned int* __restrict__ minpos_e,
                                                   unsigned int* __restrict__ maxneg_e) {
  if (blockIdx.x == 0) {  // init atomic arrays (stream order: before gemm)
    const unsigned int init_min = enc_f32(1e30f);
    const unsigned int init_max = enc_f32(-1e30f);
    for (int i = threadIdx.x; i < BDIM; i += 256) {
      minpos_e[i] = init_min;
      maxneg_e[i] = init_max;
    }
  }
  const int row  = blockIdx.x * 4 + (threadIdx.x >> 6);
  const int lane = threadIdx.x & 63;
  const float4* xr = reinterpret_cast<const float4*>(x + (size_t)row * DDIM);
  float4 v0 = xr[lane];
  float4 v1 = xr[lane + 64];
  float ss = v0.x*v0.x + v0.y*v0.y + v0.z*v0.z + v0.w*v0.w
           + v1.x*v1.x + v1.y*v1.y + v1.z*v1.z + v1.w*v1.w;
#pragma unroll
  for (int off = 32; off >= 1; off >>= 1) ss += __shfl_xor(ss, off);
  const float inv = 1.0f / fmaxf(sqrtf(ss), 1e-12f);

  ushort4 p0, p1;
  p0.x = f2bf(v0.x * inv); p0.y = f2bf(v0.y * inv);
  p0.z = f2bf(v0.z * inv); p0.w = f2bf(v0.w * inv);
  p1.x = f2bf(v1.x * inv); p1.y = f2bf(v1.y * inv);
  p1.z = f2bf(v1.z * inv); p1.w = f2bf(v1.w * inv);
  ushort4* er = reinterpret_cast<ushort4*>(e + (size_t)row * DDIM);
  er[lane]      = p0;
  er[lane + 64] = p1;
}

// ------- kernel 2: m97-structure GEMM, BK=32, 4 blocks/CU, fused reduce -----
// LDS per buffer: A [128 rows][32 k] bf16 (8 KB) + B same (8 KB).
// Row = 64 B = 4 granules of 16 B. Conflict fix: logical k-chunk gg lives at
// byte (gg ^ ((row>>1)&3))*16 -> a quarter-wave's 16 lanes cover all 8 LDS
// granule-slots twice (2-way = free). Applied on BOTH sides (rule #21):
// inverse-permuted global source (linear gload_lds dest) + permuted ds_read.
#define STAGE(buf, kt)                                                         \
  do {                                                                         \
    _Pragma("unroll")                                                          \
    for (int q = 0; q < 4; ++q) {                                              \
      const int off  = q * 4096 + tid * 16;   /* 0..16383 */                   \
      const int loff = off & 8191;                                             \
      const int row  = loff >> 6;                                              \
      const int gg   = (loff >> 4) & 3;                                        \
      const int pan  = (q < 2) ? Ibase : Jbase;                                \
      const char* src = (const char*)e + (size_t)(pan + row) * (DDIM * 2) +    \
                        (kt) * 64 + ((gg ^ ((row >> 1) & 3)) << 4);            \
      __builtin_amdgcn_global_load_lds(                                        \
          (const __attribute__((address_space(1))) void*)src,                  \
          (__attribute__((address_space(3))) void*)(&Blds[buf][off]),          \
          16, 0, 0);                                                           \
    }                                                                          \
  } while (0)

__global__ __launch_bounds__(256, 4) void gemm_reduce_kernel(
    const ushort_t* __restrict__ e, const int* __restrict__ labels,
    unsigned int* __restrict__ minpos_e, unsigned int* __restrict__ maxneg_e) {
  __shared__ __align__(16) char Blds[2][16384];
  __shared__ int Llab[256];

  const int tid  = threadIdx.x;
  const int wave = tid >> 6;
  const int lane = tid & 63;
  const int l15  = lane & 15;
  const int g    = lane >> 4;     // 0..3 (selects 8-elem k-chunk)
  const int wr   = wave >> 1;     // 0..1 row half
  const int wc   = wave & 1;      // 0..1 col half

  // bijective XCD swizzle: 1024 blocks = 8 XCDs x 128; J fastest within XCD
  const int bid  = blockIdx.x;
  const int sbid = (bid & 7) * (GRIDX / 8) + (bid >> 3);
  const int Ibase = (sbid >> 5) * BT;
  const int Jbase = (sbid & 31) * BT;

  // stage labels for this block's rows (I) and cols (J)
  if (tid < 128) Llab[tid] = labels[Ibase + tid];
  else           Llab[tid] = labels[Jbase + tid - 128];

  f32x4 acc[4][4];
#pragma unroll
  for (int m = 0; m < 4; ++m)
#pragma unroll
    for (int n = 0; n < 4; ++n) acc[m][n] = (f32x4){0.f, 0.f, 0.f, 0.f};

  STAGE(0, 0);
  __syncthreads();  // vmcnt drained at barrier: buf0 + labels ready

  for (int kt = 0; kt < NKT; ++kt) {
    if (kt + 1 < NKT) STAGE((kt + 1) & 1, kt + 1);  // async prefetch

    const char* Ab = Blds[kt & 1];
    const char* Bb = Blds[kt & 1] + 8192;
    bf16x8 a[4], b[4];
#pragma unroll
    for (int m = 0; m < 4; ++m) {
      const int row = wr * 64 + m * 16 + l15;
      a[m] = *reinterpret_cast<const bf16x8*>(
          Ab + row * 64 + ((g ^ ((row >> 1) & 3)) << 4));
    }
#pragma unroll
    for (int n = 0; n < 4; ++n) {
      const int row = wc * 64 + n * 16 + l15;
      b[n] = *reinterpret_cast<const bf16x8*>(
          Bb + row * 64 + ((g ^ ((row >> 1) & 3)) << 4));
    }
#pragma unroll
    for (int m = 0; m < 4; ++m)
#pragma unroll
      for (int n = 0; n < 4; ++n)
        acc[m][n] = __builtin_amdgcn_mfma_f32_16x16x32_bf16(a[m], b[n],
                                                            acc[m][n], 0, 0, 0);
    __syncthreads();  // staged(kt+1) complete + cur buffer release
  }

  // ---- fused epilogue: per-COLUMN masked min/max (S symmetric) ----------
  // C/D 16x16 layout: col = l15, row = g*4 + reg. A lane's 16 values all sit
  // in column (n, l15) -> in-lane reduce + 2 shuffles across g.
  float cmp[4], cmx[4];
  int lj[4], gj[4];
#pragma unroll
  for (int n = 0; n < 4; ++n) {
    cmp[n] = 1e30f; cmx[n] = -1e30f;
    gj[n]  = Jbase + wc * 64 + n * 16 + l15;
    lj[n]  = Llab[128 + wc * 64 + n * 16 + l15];
  }
#pragma unroll
  for (int m = 0; m < 4; ++m) {
#pragma unroll
    for (int r = 0; r < 4; ++r) {
      const int rloc = wr * 64 + m * 16 + g * 4 + r;
      const int li   = Llab[rloc];
      const int gi   = Ibase + rloc;
#pragma unroll
      for (int n = 0; n < 4; ++n) {
        const float v = acc[m][n][r];
        if (li == lj[n]) {
          if (gi != gj[n]) cmp[n] = fminf(cmp[n], v);
        } else {
          cmx[n] = fmaxf(cmx[n], v);
        }
      }
    }
  }
  // reduce across the 4 lanes (g = 0..3) sharing each column
#pragma unroll
  for (int off = 16; off <= 32; off <<= 1) {
#pragma unroll
    for (int n = 0; n < 4; ++n) {
      cmp[n] = fminf(cmp[n], __shfl_xor(cmp[n], off));
      cmx[n] = fmaxf(cmx[n], __shfl_xor(cmx[n], off));
    }
  }
  if (g == 0) {
#pragma unroll
    for (int n = 0; n < 4; ++n) {
      if (cmp[n] < 1e29f)  atomicMin(&minpos_e[gj[n]], enc_f32(cmp[n]));
      if (cmx[n] > -1e29f) atomicMax(&maxneg_e[gj[n]], enc_f32(cmx[n]));
    }
  }
}

// ---------------- kernel 3: combine -> scalar loss ----------------
__global__ __launch_bounds__(1024) void finalize_kernel(
    const unsigned int* __restrict__ minpos_e, const unsigned int* __restrict__ maxneg_e,
    float* __restrict__ out) {
  const int tid = threadIdx.x;
  float sum = 0.f;
  int cnt = 0;
  for (int row = tid; row < BDIM; row += 1024) {
    const float mp = dec_f32(minpos_e[row]);
    const float mn = dec_f32(maxneg_e[row]);
    if (mp < 1e29f && mn > -1e29f) {
      // hp - hn + margin = (1-mp) - (1-mn) + 0.2 = mn - mp + 0.2
      sum += fmaxf(0.f, mn - mp + 0.2f);
      cnt += 1;
    }
  }
#pragma unroll
  for (int off = 32; off >= 1; off >>= 1) {
    sum += __shfl_xor(sum, off);
    cnt += __shfl_xor(cnt, off);
  }
  __shared__ float wsum[16];
  __shared__ int   wcnt[16];
  const int wv = tid >> 6, ln = tid & 63;
  if (ln == 0) { wsum[wv] = sum; wcnt[wv] = cnt; }
  __syncthreads();
  if (tid == 0) {
    float S = 0.f; int C = 0;
    for (int w = 0; w < 16; ++w) { S += wsum[w]; C += wcnt[w]; }
    out[0] = S / (float)(C > 0 ? C : 1);
  }
}

extern "C" void kernel_launch(void* const* d_in, const int* in_sizes, int n_in,
                              void* d_out, int out_size, void* d_ws, size_t ws_size,
                              hipStream_t stream) {
  const float* x      = (const float*)d_in[0];
  const int*   labels = (const int*)d_in[1];
  float* out = (float*)d_out;

  char* ws = (char*)d_ws;
  ushort_t* e            = (ushort_t*)ws;                            // 4 MB bf16 E
  unsigned int* minpos_e = (unsigned int*)(ws + (size_t)BDIM * DDIM * 2);
  unsigned int* maxneg_e = minpos_e + BDIM;

  norm_kernel<<<BDIM / 4, 256, 0, stream>>>(x, e, minpos_e, maxneg_e);
  gemm_reduce_kernel<<<GRIDX, 256, 0, stream>>>(e, labels, minpos_e, maxneg_e);
  finalize_kernel<<<1, 1024, 0, stream>>>(minpos_e, maxneg_e, out);
}